// Round 1
// baseline (242.281 us; speedup 1.0000x reference)
//
#include <hip/hip_runtime.h>

#define BATCH 4
#define CH    256
#define NTOK  4096
#define DQK   32

typedef __attribute__((ext_vector_type(4))) float  f32x4;
typedef __attribute__((ext_vector_type(2))) float  f32x2;
typedef __attribute__((ext_vector_type(8))) __bf16 bf16x8;
typedef __attribute__((ext_vector_type(2))) unsigned int u32x2;
typedef __attribute__((ext_vector_type(4))) unsigned int u32x4;

// round-to-nearest-even float -> bf16 bits
static __device__ __forceinline__ unsigned short f2bf(float f) {
    unsigned int u = __builtin_bit_cast(unsigned int, f);
    unsigned int r = u + 0x7FFFu + ((u >> 16) & 1u);
    return (unsigned short)(r >> 16);
}
static __device__ __forceinline__ unsigned int pack2(float a, float b) {
    return (unsigned int)f2bf(a) | ((unsigned int)f2bf(b) << 16);
}

// ---------------------------------------------------------------------------
// Kernel 0: convert Wq|Wk|Wv -> Wbf [320 rows][256 c] bf16; zero Mk scalars.
// ---------------------------------------------------------------------------
__global__ __launch_bounds__(256)
void wconv(const float* __restrict__ Wq, const float* __restrict__ Wk,
           const float* __restrict__ Wv, unsigned short* __restrict__ Wbf,
           unsigned int* __restrict__ Mk)
{
    if (blockIdx.x == 0 && threadIdx.x < BATCH) Mk[threadIdx.x] = 0u;
    const int id = (blockIdx.x * 256 + threadIdx.x) * 4;
    const int r  = id >> 8;
    const int c  = id & 255;
    const float* src = (r < 32) ? (Wq + r * 256 + c)
                     : (r < 64) ? (Wk + (r - 32) * 256 + c)
                                : (Wv + (size_t)(r - 64) * 256 + c);
    float v0 = src[0], v1 = src[1], v2 = src[2], v3 = src[3];
    u32x2 p = {pack2(v0, v1), pack2(v2, v3)};
    *reinterpret_cast<u32x2*>(Wbf + id) = p;
}

// ---------------------------------------------------------------------------
// Kernel 1: QKV projection, barrier-free main loop. 16-token blocks (grid
// 1024 = 4 blocks/CU = 16 waves/CU). Each wave builds its MFMA A-fragment
// directly from global x (8 strided dwords per k-step; the 16KB x-tile is
// L1-resident so the 4 waves' redundant reads are cheap). 5 row-tiles/wave.
// Fully unrolled: ~104 independent VMEM + 40 MFMA per wave, no barriers
// until the V-transpose epilogue. Also per-batch max||k||^2 -> Mk[b].
// ---------------------------------------------------------------------------
__global__ __launch_bounds__(256, 4)
void qkv_proj(const float* __restrict__ x,
              const float* __restrict__ pbq, const float* __restrict__ pbk,
              const float* __restrict__ pbv,
              const unsigned short* __restrict__ Wbf,
              unsigned short* __restrict__ Qh,
              unsigned short* __restrict__ Kh,
              unsigned short* __restrict__ Vh,
              unsigned int* __restrict__ Mk)
{
    const int t    = threadIdx.x;
    const int wave = t >> 6;
    const int lane = t & 63;
    const int low  = lane & 15;
    const int quad = lane >> 4;
    const int tok0 = blockIdx.x * 16;
    const int b    = tok0 >> 12;
    const int nl0  = tok0 & (NTOK - 1);

    __shared__ unsigned short ob[256 * 24];     // V transpose [c][24]

    f32x4 acc[5];
    #pragma unroll
    for (int j = 0; j < 5; ++j) {
        const int rtg = wave * 5 + j;
        float bb = (rtg < 2) ? pbq[rtg * 16 + low]
                 : (rtg < 4) ? pbk[(rtg - 2) * 16 + low]
                             : pbv[(rtg - 4) * 16 + low];
        f32x4 z = {bb, bb, bb, bb};
        acc[j] = z;
    }

    // per-lane x base: token = tok0+low; channel added per load
    const float* xb = x + (size_t)b * CH * NTOK + nl0 + low;

    #pragma unroll
    for (int k0 = 0; k0 < 8; ++k0) {
        const int cbase = k0 * 32 + quad * 8;
        float xv[8];
        #pragma unroll
        for (int e = 0; e < 8; ++e)
            xv[e] = xb[(size_t)(cbase + e) * NTOK];
        u32x4 ap = {pack2(xv[0], xv[1]), pack2(xv[2], xv[3]),
                    pack2(xv[4], xv[5]), pack2(xv[6], xv[7])};
        const bf16x8 af = __builtin_bit_cast(bf16x8, ap);
        #pragma unroll
        for (int j = 0; j < 5; ++j) {
            const int rtg = wave * 5 + j;
            const bf16x8 bf = *reinterpret_cast<const bf16x8*>(
                Wbf + (size_t)(rtg * 16 + low) * 256 + k0 * 32 + quad * 8);
            acc[j] = __builtin_amdgcn_mfma_f32_16x16x32_bf16(af, bf, acc[j], 0, 0, 0);
        }
    }

    // ---- Q/K epilogue + ||k||^2 max (wave 0: rtg 0..3) ----
    #pragma unroll
    for (int j = 0; j < 5; ++j) {
        const int rtg = wave * 5 + j;
        if (rtg < 4) {
            unsigned short* dst = (rtg < 2) ? Qh : Kh;
            const int wr = (rtg & 1) * 16 + low;
            #pragma unroll
            for (int reg = 0; reg < 4; ++reg) {
                const int token = tok0 + quad * 4 + reg;
                dst[(size_t)token * DQK + wr] = f2bf(acc[j][reg]);
            }
        }
    }
    if (wave == 0) {
        f32x4 kk = acc[2] * acc[2] + acc[3] * acc[3];
        #pragma unroll
        for (int mask = 1; mask <= 8; mask <<= 1)
            #pragma unroll
            for (int reg = 0; reg < 4; ++reg)
                kk[reg] += __shfl_xor(kk[reg], mask);
        if (low == 0) {
            #pragma unroll
            for (int reg = 0; reg < 4; ++reg)
                atomicMax(&Mk[b], __builtin_bit_cast(unsigned int, kk[reg]));
        }
    }

    // ---- V epilogue: transpose via LDS ----
    #pragma unroll
    for (int j = 0; j < 5; ++j) {
        const int rtg = wave * 5 + j;
        if (rtg >= 4) {
            const int c = (rtg - 4) * 16 + low;
            #pragma unroll
            for (int reg = 0; reg < 4; ++reg)
                ob[c * 24 + quad * 4 + reg] = f2bf(acc[j][reg]);
        }
    }
    __syncthreads();
    {
        const unsigned int* obd = (const unsigned int*)ob;
        const int h = t & 1;
        #pragma unroll
        for (int pass = 0; pass < 2; ++pass) {
            const int c = (t >> 1) + pass * 128;
            const u32x4 v = *reinterpret_cast<const u32x4*>(obd + c * 12 + h * 4);
            *reinterpret_cast<u32x4*>(
                Vh + ((size_t)b * CH + c) * NTOK + nl0 + h * 8) = v;
        }
    }
}

// ---------------------------------------------------------------------------
// Kernel 2: flash attention, static Cauchy-Schwarz softmax bound, software-
// pipelined with double-buffered P. 512 thr = 8 waves = kg(4) x ch(2);
// 64 q/block, acc[4][8]; each V fragment feeds 4 MFMAs. Loop:
//   sync; S(i+1)->Pbuf[(i+1)&1]; PV(i)<-Pbuf[i&1]
// -> ONE barrier/iter. Buffer selected by OFFSET arithmetic (array-of-LDS-
// pointers initializer is rejected by the gfx950 backend — R7 compile fail).
// Grid 256 flat, XCD swizzle pins each batch's K/V to one XCD pair's L2.
// ---------------------------------------------------------------------------
__global__ __launch_bounds__(512, 2)
void attn(const float* __restrict__ x,
          const unsigned short* __restrict__ Qh,
          const unsigned short* __restrict__ Kh,
          const unsigned short* __restrict__ Vh,
          const unsigned int* __restrict__ Mk,
          float* __restrict__ out)
{
    const int t    = threadIdx.x;
    const int wave = t >> 6;                 // 0..7
    const int kg   = wave & 3;               // keygroup
    const int ch   = wave >> 2;              // channel half
    const int lane = t & 63;
    const int low  = lane & 15;
    const int quad = lane >> 4;

    const int beta = blockIdx.x;             // XCD swizzle (perf heuristic)
    const int b    = (beta & 7) >> 1;
    const int q0   = (((beta >> 3) * 2) + (beta & 1)) * 64;

    // smem dwords: [0,9216) Pbuf0 (4 kg x 64 q x 36 dw), [9216,18432) Pbuf1,
    // [18432,18688) lbuf. Merge slabs (8 x 64 x 22 = 11264 dw) alias Pbuf0+.
    __shared__ float smem[18432 + 256];
    unsigned int* Pbase = (unsigned int*)smem;
    float* lbuf = smem + 18432;

    const float LOG2E = 1.44269504088896f;

    bf16x8 qfrag[2];
    float  m2[2];
    {
        const float M2 = __builtin_bit_cast(float, Mk[b]);
        #pragma unroll
        for (int j = 0; j < 2; ++j) {
            const int qs = 2 * ch + j;
            qfrag[j] = *reinterpret_cast<const bf16x8*>(
                Qh + (size_t)(b * NTOK + q0 + qs * 16 + low) * DQK + quad * 8);
            float qn2 = 0.f;
            #pragma unroll
            for (int e = 0; e < 8; ++e) {
                float qv = (float)qfrag[j][e];
                qn2 += qv * qv;
            }
            qn2 += __shfl_xor(qn2, 16);
            qn2 += __shfl_xor(qn2, 32);
            m2[j] = __builtin_sqrtf(qn2 * M2) * (1.02f * LOG2E);
        }
    }

    f32x4 acc[4][8];
    #pragma unroll
    for (int qs = 0; qs < 4; ++qs)
        #pragma unroll
        for (int ct = 0; ct < 8; ++ct) { f32x4 z = {0.f,0.f,0.f,0.f}; acc[qs][ct] = z; }
    float l_s[2] = {0.f, 0.f};

    const unsigned short* Kb = Kh + (size_t)b * NTOK * DQK;
    const unsigned short* Vb = Vh + (size_t)b * CH * NTOK;

    #define S_PHASE(ii, buf)                                                    \
    {                                                                           \
        const int n0s = ((ii) * 4 + kg) * 64;                                   \
        bf16x8 kf[4];                                                           \
        _Pragma("unroll")                                                       \
        for (int kt = 0; kt < 4; ++kt)                                          \
            kf[kt] = *reinterpret_cast<const bf16x8*>(                          \
                Kb + (size_t)(n0s + kt * 16 + low) * DQK + quad * 8);           \
        _Pragma("unroll")                                                       \
        for (int j = 0; j < 2; ++j) {                                           \
            const int qs = 2 * ch + j;                                          \
            f32x4 S[4];                                                         \
            _Pragma("unroll")                                                   \
            for (int kt = 0; kt < 4; ++kt) {                                    \
                f32x4 z = {0.f,0.f,0.f,0.f};                                    \
                S[kt] = __builtin_amdgcn_mfma_f32_16x16x32_bf16(kf[kt],         \
                            qfrag[j], z, 0, 0, 0);                              \
            }                                                                   \
            float sum = 0.f;                                                    \
            unsigned int* pq = Pbase + (buf) * 9216 + kg * 2304                 \
                               + (qs * 16 + low) * 36 + quad * 2;               \
            _Pragma("unroll")                                                   \
            for (int kt = 0; kt < 4; ++kt) {                                    \
                float p0 = __builtin_amdgcn_exp2f(S[kt][0] * LOG2E - m2[j]);    \
                float p1 = __builtin_amdgcn_exp2f(S[kt][1] * LOG2E - m2[j]);    \
                float p2 = __builtin_amdgcn_exp2f(S[kt][2] * LOG2E - m2[j]);    \
                float p3 = __builtin_amdgcn_exp2f(S[kt][3] * LOG2E - m2[j]);    \
                sum += (p0 + p1) + (p2 + p3);                                   \
                u32x2 w2 = {pack2(p0, p1), pack2(p2, p3)};                      \
                *reinterpret_cast<u32x2*>(pq + kt * 8) = w2;                    \
            }                                                                   \
            l_s[j] += sum;                                                      \
        }                                                                       \
    }

    S_PHASE(0, 0)

    for (int i = 0; i < 16; ++i) {
        __syncthreads();                     // S(i) visible to partner wave

        if (i < 15) S_PHASE(i + 1, (i + 1) & 1)

        // ---- PV(i) from Pbuf[i&1] ----
        {
            const int n0 = (i * 4 + kg) * 64;
            const unsigned short* Phh =
                (const unsigned short*)(Pbase + (i & 1) * 9216);
            #pragma unroll
            for (int s = 0; s < 2; ++s) {
                bf16x8 pf[4];
                #pragma unroll
                for (int qs = 0; qs < 4; ++qs)
                    pf[qs] = *reinterpret_cast<const bf16x8*>(
                        Phh + kg * 4608 + (qs * 16 + low) * 72 + s * 32 + quad * 8);
                #pragma unroll
                for (int ct = 0; ct < 8; ++ct) {
                    const bf16x8 vf = *reinterpret_cast<const bf16x8*>(
                        Vb + (size_t)(ch * 128 + ct * 16 + low) * NTOK
                           + n0 + s * 32 + quad * 8);
                    #pragma unroll
                    for (int qs = 0; qs < 4; ++qs)
                        acc[qs][ct] = __builtin_amdgcn_mfma_f32_16x16x32_bf16(
                            vf, pf[qs], acc[qs][ct], 0, 0, 0);
                }
            }
        }
    }
    #undef S_PHASE

    // ---- publish per-keygroup l ----
    #pragma unroll
    for (int j = 0; j < 2; ++j) {
        l_s[j] += __shfl_xor(l_s[j], 16);
        l_s[j] += __shfl_xor(l_s[j], 32);
    }
    if (quad == 0) {
        #pragma unroll
        for (int j = 0; j < 2; ++j)
            lbuf[kg * 64 + (2 * ch + j) * 16 + low] = l_s[j];
    }

    // ---- merge 4 kg-partials, 32 channels (16 per ch-half) per round ----
    const int q = t & 63;
    const int u = t >> 6;                    // 0..7
    float invl = 0.f;
    for (int rd = 0; rd < 8; ++rd) {
        #pragma unroll
        for (int qs = 0; qs < 4; ++qs) {
            float* sl = smem + wave * 1408 + (qs * 16 + low) * 22 + quad * 4;
            f32x2 lo = {acc[qs][rd][0], acc[qs][rd][1]};
            f32x2 hi = {acc[qs][rd][2], acc[qs][rd][3]};
            *reinterpret_cast<f32x2*>(sl)     = lo;
            *reinterpret_cast<f32x2*>(sl + 2) = hi;
        }
        __syncthreads();
        if (rd == 0)
            invl = 1.0f / (((lbuf[q] + lbuf[64 + q]) + (lbuf[128 + q] + lbuf[192 + q])));

        #pragma unroll
        for (int p = 0; p < 4; ++p) {
            const int half = p >> 1;
            const int c15  = u * 2 + (p & 1);            // 0..15
            const int wb   = half * 4;
            float O = (smem[(wb + 0) * 1408 + q * 22 + c15]
                     + smem[(wb + 1) * 1408 + q * 22 + c15])
                    + (smem[(wb + 2) * 1408 + q * 22 + c15]
                     + smem[(wb + 3) * 1408 + q * 22 + c15]);
            const int c = half * 128 + rd * 16 + c15;
            const size_t idx = (size_t)(b * CH + c) * NTOK + q0 + q;
            out[idx] = x[idx] + O * invl;
        }
        __syncthreads();
    }
}

extern "C" void kernel_launch(void* const* d_in, const int* in_sizes, int n_in,
                              void* d_out, int out_size, void* d_ws, size_t ws_size,
                              hipStream_t stream) {
    const float* x  = (const float*)d_in[0];
    const float* Wq = (const float*)d_in[1];
    const float* bq = (const float*)d_in[2];
    const float* Wk = (const float*)d_in[3];
    const float* bk = (const float*)d_in[4];
    const float* Wv = (const float*)d_in[5];
    const float* bv = (const float*)d_in[6];
    float* out = (float*)d_out;

    unsigned short* Qh  = (unsigned short*)d_ws;                 // [B,N,32] bf16
    unsigned short* Kh  = Qh  + (size_t)BATCH * NTOK * DQK;      // [B,N,32] bf16
    unsigned short* Vh  = Kh  + (size_t)BATCH * NTOK * DQK;      // [B,C,N] bf16
    unsigned short* Wbf = Vh  + (size_t)BATCH * CH * NTOK;       // [320,256] bf16
    unsigned int*   Mk  = (unsigned int*)(Wbf + 320 * 256);      // [B] max||k||^2

    wconv<<<dim3(80), dim3(256), 0, stream>>>(Wq, Wk, Wv, Wbf, Mk);
    qkv_proj<<<dim3(1024), dim3(256), 0, stream>>>(x, bq, bk, bv, Wbf,
                                                   Qh, Kh, Vh, Mk);
    attn<<<dim3(256), dim3(512), 0, stream>>>(x, Qh, Kh, Vh, Mk, out);
}

// Round 2
// 222.480 us; speedup vs baseline: 1.0890x; 1.0890x over previous
//
#include <hip/hip_runtime.h>

#define BATCH 4
#define CH    256
#define NTOK  4096
#define DQK   32

typedef __attribute__((ext_vector_type(4))) float  f32x4;
typedef __attribute__((ext_vector_type(2))) float  f32x2;
typedef __attribute__((ext_vector_type(8))) __bf16 bf16x8;
typedef __attribute__((ext_vector_type(2))) unsigned int u32x2;
typedef __attribute__((ext_vector_type(4))) unsigned int u32x4;

// round-to-nearest-even float -> bf16 bits (cold paths)
static __device__ __forceinline__ unsigned short f2bf(float f) {
    unsigned int u = __builtin_bit_cast(unsigned int, f);
    unsigned int r = u + 0x7FFFu + ((u >> 16) & 1u);
    return (unsigned short)(r >> 16);
}
static __device__ __forceinline__ unsigned int pack2(float a, float b) {
    return (unsigned int)f2bf(a) | ((unsigned int)f2bf(b) << 16);
}
// hot-path pack: single HW instr, RTNE, a->lo b->hi
static __device__ __forceinline__ unsigned int cvt_pk_bf16(float a, float b) {
    unsigned int r;
    asm("v_cvt_pk_bf16_f32 %0, %1, %2" : "=v"(r) : "v"(a), "v"(b));
    return r;
}

// ---------------------------------------------------------------------------
// Kernel 0: convert Wq|Wk|Wv -> Wbf [320 rows][256 c] bf16; zero Mk scalars.
// ---------------------------------------------------------------------------
__global__ __launch_bounds__(256)
void wconv(const float* __restrict__ Wq, const float* __restrict__ Wk,
           const float* __restrict__ Wv, unsigned short* __restrict__ Wbf,
           unsigned int* __restrict__ Mk)
{
    if (blockIdx.x == 0 && threadIdx.x < BATCH) Mk[threadIdx.x] = 0u;
    const int id = (blockIdx.x * 256 + threadIdx.x) * 4;
    const int r  = id >> 8;
    const int c  = id & 255;
    const float* src = (r < 32) ? (Wq + r * 256 + c)
                     : (r < 64) ? (Wk + (r - 32) * 256 + c)
                                : (Wv + (size_t)(r - 64) * 256 + c);
    float v0 = src[0], v1 = src[1], v2 = src[2], v3 = src[3];
    u32x2 p = {pack2(v0, v1), pack2(v2, v3)};
    *reinterpret_cast<u32x2*>(Wbf + id) = p;
}

// ---------------------------------------------------------------------------
// Kernel 1: QKV projection, barrier-free main loop. 16-token blocks (grid
// 1024 = 4 blocks/CU = 16 waves/CU). Pack via v_cvt_pk_bf16_f32 (1 instr vs
// ~9 for the hand RNE pack — the main loop was pack-VALU-heavy).
// ---------------------------------------------------------------------------
__global__ __launch_bounds__(256, 4)
void qkv_proj(const float* __restrict__ x,
              const float* __restrict__ pbq, const float* __restrict__ pbk,
              const float* __restrict__ pbv,
              const unsigned short* __restrict__ Wbf,
              unsigned short* __restrict__ Qh,
              unsigned short* __restrict__ Kh,
              unsigned short* __restrict__ Vh,
              unsigned int* __restrict__ Mk)
{
    const int t    = threadIdx.x;
    const int wave = t >> 6;
    const int lane = t & 63;
    const int low  = lane & 15;
    const int quad = lane >> 4;
    const int tok0 = blockIdx.x * 16;
    const int b    = tok0 >> 12;
    const int nl0  = tok0 & (NTOK - 1);

    __shared__ unsigned short ob[256 * 24];     // V transpose [c][24]

    f32x4 acc[5];
    #pragma unroll
    for (int j = 0; j < 5; ++j) {
        const int rtg = wave * 5 + j;
        float bb = (rtg < 2) ? pbq[rtg * 16 + low]
                 : (rtg < 4) ? pbk[(rtg - 2) * 16 + low]
                             : pbv[(rtg - 4) * 16 + low];
        f32x4 z = {bb, bb, bb, bb};
        acc[j] = z;
    }

    const float* xb = x + (size_t)b * CH * NTOK + nl0 + low;

    #pragma unroll
    for (int k0 = 0; k0 < 8; ++k0) {
        const int cbase = k0 * 32 + quad * 8;
        float xv[8];
        #pragma unroll
        for (int e = 0; e < 8; ++e)
            xv[e] = xb[(size_t)(cbase + e) * NTOK];
        u32x4 ap = {cvt_pk_bf16(xv[0], xv[1]), cvt_pk_bf16(xv[2], xv[3]),
                    cvt_pk_bf16(xv[4], xv[5]), cvt_pk_bf16(xv[6], xv[7])};
        const bf16x8 af = __builtin_bit_cast(bf16x8, ap);
        #pragma unroll
        for (int j = 0; j < 5; ++j) {
            const int rtg = wave * 5 + j;
            const bf16x8 bf = *reinterpret_cast<const bf16x8*>(
                Wbf + (size_t)(rtg * 16 + low) * 256 + k0 * 32 + quad * 8);
            acc[j] = __builtin_amdgcn_mfma_f32_16x16x32_bf16(af, bf, acc[j], 0, 0, 0);
        }
    }

    // ---- Q/K epilogue + ||k||^2 max (wave 0: rtg 0..3) ----
    #pragma unroll
    for (int j = 0; j < 5; ++j) {
        const int rtg = wave * 5 + j;
        if (rtg < 4) {
            unsigned short* dst = (rtg < 2) ? Qh : Kh;
            const int wr = (rtg & 1) * 16 + low;
            #pragma unroll
            for (int reg = 0; reg < 4; ++reg) {
                const int token = tok0 + quad * 4 + reg;
                dst[(size_t)token * DQK + wr] = f2bf(acc[j][reg]);
            }
        }
    }
    if (wave == 0) {
        f32x4 kk = acc[2] * acc[2] + acc[3] * acc[3];
        #pragma unroll
        for (int mask = 1; mask <= 8; mask <<= 1)
            #pragma unroll
            for (int reg = 0; reg < 4; ++reg)
                kk[reg] += __shfl_xor(kk[reg], mask);
        if (low == 0) {
            #pragma unroll
            for (int reg = 0; reg < 4; ++reg)
                atomicMax(&Mk[b], __builtin_bit_cast(unsigned int, kk[reg]));
        }
    }

    // ---- V epilogue: transpose via LDS ----
    #pragma unroll
    for (int j = 0; j < 5; ++j) {
        const int rtg = wave * 5 + j;
        if (rtg >= 4) {
            const int c = (rtg - 4) * 16 + low;
            #pragma unroll
            for (int reg = 0; reg < 4; ++reg)
                ob[c * 24 + quad * 4 + reg] = f2bf(acc[j][reg]);
        }
    }
    __syncthreads();
    {
        const unsigned int* obd = (const unsigned int*)ob;
        const int h = t & 1;
        #pragma unroll
        for (int pass = 0; pass < 2; ++pass) {
            const int c = (t >> 1) + pass * 128;
            const u32x4 v = *reinterpret_cast<const u32x4*>(obd + c * 12 + h * 4);
            *reinterpret_cast<u32x4*>(
                Vh + ((size_t)b * CH + c) * NTOK + nl0 + h * 8) = v;
        }
    }
}

// ---------------------------------------------------------------------------
// Kernel 2: flash attention, BARRIER-FREE main loop.
// Change vs R0: P is wave-PRIVATE. Each wave computes S for ALL 4 q-subtiles
// of its keygroup (S duplicated across the 2 ch-waves: +11% MFMA, +32 exp2/
// lane/iter) so PV never reads another wave's P -> zero __syncthreads in the
// 16-iteration loop. R0 counters showed MfmaUtil 14%/VALU 17%/Occ 21% with
// 1 block/CU: the per-iter barrier coupled all 8 waves to the slowest wave's
// K-load latency. Now waves free-run; DS ops are in-order per wave and P is
// double-buffered, so S(i+1) writes buf^1 while PV(i) reads buf -> race-free
// without sync. LDS: 2 bufs x 8 waves x 2304 dw = 147 KB (1 block/CU as
// before). s_setprio(1) wraps the PV MFMA cluster (T5: waves now drift).
// ---------------------------------------------------------------------------
__global__ __launch_bounds__(512, 2)
void attn(const float* __restrict__ x,
          const unsigned short* __restrict__ Qh,
          const unsigned short* __restrict__ Kh,
          const unsigned short* __restrict__ Vh,
          const unsigned int* __restrict__ Mk,
          float* __restrict__ out)
{
    const int t    = threadIdx.x;
    const int wave = t >> 6;                 // 0..7
    const int kg   = wave & 3;               // keygroup
    const int ch   = wave >> 2;              // channel half (PV only)
    const int lane = t & 63;
    const int low  = lane & 15;
    const int quad = lane >> 4;

    const int beta = blockIdx.x;             // XCD swizzle (perf heuristic)
    const int b    = (beta & 7) >> 1;
    const int q0   = (((beta >> 3) * 2) + (beta & 1)) * 64;

    // dwords: [0,36864) private P, dbuf: buf*18432 + wave*2304 + row*36;
    // [36864,37120) lbuf. Merge slabs (8 x 1408 dw) alias the P region.
    __shared__ float smem[36864 + 256];
    unsigned int* Pbase = (unsigned int*)smem;
    float* lbuf = smem + 36864;

    const float LOG2E = 1.44269504088896f;

    bf16x8 qfrag[4];
    float  m2[4];
    {
        const float M2 = __builtin_bit_cast(float, Mk[b]);
        #pragma unroll
        for (int j = 0; j < 4; ++j) {
            qfrag[j] = *reinterpret_cast<const bf16x8*>(
                Qh + (size_t)(b * NTOK + q0 + j * 16 + low) * DQK + quad * 8);
            float qn2 = 0.f;
            #pragma unroll
            for (int e = 0; e < 8; ++e) {
                float qv = (float)qfrag[j][e];
                qn2 += qv * qv;
            }
            qn2 += __shfl_xor(qn2, 16);
            qn2 += __shfl_xor(qn2, 32);
            m2[j] = __builtin_sqrtf(qn2 * M2) * (1.02f * LOG2E);
        }
    }

    f32x4 acc[4][8];
    #pragma unroll
    for (int qs = 0; qs < 4; ++qs)
        #pragma unroll
        for (int ct = 0; ct < 8; ++ct) { f32x4 z = {0.f,0.f,0.f,0.f}; acc[qs][ct] = z; }
    float l_s[4] = {0.f, 0.f, 0.f, 0.f};

    const unsigned short* Kb = Kh + (size_t)b * NTOK * DQK;
    const unsigned short* Vb = Vh + (size_t)b * CH * NTOK;

    // S for ALL 4 q-subtiles, own keygroup, into OWN P region (no sharing).
    #define S_PHASE(ii, buf)                                                    \
    {                                                                           \
        const int n0s = ((ii) * 4 + kg) * 64;                                   \
        bf16x8 kf[4];                                                           \
        _Pragma("unroll")                                                       \
        for (int kt = 0; kt < 4; ++kt)                                          \
            kf[kt] = *reinterpret_cast<const bf16x8*>(                          \
                Kb + (size_t)(n0s + kt * 16 + low) * DQK + quad * 8);           \
        _Pragma("unroll")                                                       \
        for (int j = 0; j < 4; ++j) {                                           \
            f32x4 S[4];                                                         \
            _Pragma("unroll")                                                   \
            for (int kt = 0; kt < 4; ++kt) {                                    \
                f32x4 z = {0.f,0.f,0.f,0.f};                                    \
                S[kt] = __builtin_amdgcn_mfma_f32_16x16x32_bf16(kf[kt],         \
                            qfrag[j], z, 0, 0, 0);                              \
            }                                                                   \
            float sum = 0.f;                                                    \
            unsigned int* pq = Pbase + (buf) * 18432 + wave * 2304              \
                               + (j * 16 + low) * 36 + quad * 2;                \
            _Pragma("unroll")                                                   \
            for (int kt = 0; kt < 4; ++kt) {                                    \
                float p0 = __builtin_amdgcn_exp2f(S[kt][0] * LOG2E - m2[j]);    \
                float p1 = __builtin_amdgcn_exp2f(S[kt][1] * LOG2E - m2[j]);    \
                float p2 = __builtin_amdgcn_exp2f(S[kt][2] * LOG2E - m2[j]);    \
                float p3 = __builtin_amdgcn_exp2f(S[kt][3] * LOG2E - m2[j]);    \
                sum += (p0 + p1) + (p2 + p3);                                   \
                u32x2 w2 = {cvt_pk_bf16(p0, p1), cvt_pk_bf16(p2, p3)};          \
                *reinterpret_cast<u32x2*>(pq + kt * 8) = w2;                    \
            }                                                                   \
            l_s[j] += sum;                                                      \
        }                                                                       \
    }

    S_PHASE(0, 0)

    for (int i = 0; i < 16; ++i) {
        if (i < 15) S_PHASE(i + 1, (i + 1) & 1)

        // ---- PV(i) from own Pbuf[i&1] ----
        {
            const int n0 = (i * 4 + kg) * 64;
            const unsigned short* Phh =
                (const unsigned short*)(Pbase + (i & 1) * 18432 + wave * 2304);
            __builtin_amdgcn_s_setprio(1);
            #pragma unroll
            for (int s = 0; s < 2; ++s) {
                bf16x8 pf[4];
                #pragma unroll
                for (int qs = 0; qs < 4; ++qs)
                    pf[qs] = *reinterpret_cast<const bf16x8*>(
                        Phh + (qs * 16 + low) * 72 + s * 32 + quad * 8);
                #pragma unroll
                for (int ct = 0; ct < 8; ++ct) {
                    const bf16x8 vf = *reinterpret_cast<const bf16x8*>(
                        Vb + (size_t)(ch * 128 + ct * 16 + low) * NTOK
                           + n0 + s * 32 + quad * 8);
                    #pragma unroll
                    for (int qs = 0; qs < 4; ++qs)
                        acc[qs][ct] = __builtin_amdgcn_mfma_f32_16x16x32_bf16(
                            vf, pf[qs], acc[qs][ct], 0, 0, 0);
                }
            }
            __builtin_amdgcn_s_setprio(0);
        }
    }
    #undef S_PHASE

    // ---- publish per-keygroup l (each wave computed all 4; publish own 2) ----
    #pragma unroll
    for (int j = 0; j < 4; ++j) {
        l_s[j] += __shfl_xor(l_s[j], 16);
        l_s[j] += __shfl_xor(l_s[j], 32);
    }
    if (quad == 0) {
        #pragma unroll
        for (int jj = 0; jj < 2; ++jj) {
            const int qs = 2 * ch + jj;
            lbuf[kg * 64 + qs * 16 + low] = l_s[qs];
        }
    }
    __syncthreads();   // waves may have drifted; all must be done with P

    // ---- merge 4 kg-partials, 32 channels (16 per ch-half) per round ----
    const int q = t & 63;
    const int u = t >> 6;                    // 0..7
    float invl = 0.f;
    for (int rd = 0; rd < 8; ++rd) {
        #pragma unroll
        for (int qs = 0; qs < 4; ++qs) {
            float* sl = smem + wave * 1408 + (qs * 16 + low) * 22 + quad * 4;
            f32x2 lo = {acc[qs][rd][0], acc[qs][rd][1]};
            f32x2 hi = {acc[qs][rd][2], acc[qs][rd][3]};
            *reinterpret_cast<f32x2*>(sl)     = lo;
            *reinterpret_cast<f32x2*>(sl + 2) = hi;
        }
        __syncthreads();
        if (rd == 0)
            invl = 1.0f / (((lbuf[q] + lbuf[64 + q]) + (lbuf[128 + q] + lbuf[192 + q])));

        #pragma unroll
        for (int p = 0; p < 4; ++p) {
            const int half = p >> 1;
            const int c15  = u * 2 + (p & 1);            // 0..15
            const int wb   = half * 4;
            float O = (smem[(wb + 0) * 1408 + q * 22 + c15]
                     + smem[(wb + 1) * 1408 + q * 22 + c15])
                    + (smem[(wb + 2) * 1408 + q * 22 + c15]
                     + smem[(wb + 3) * 1408 + q * 22 + c15]);
            const int c = half * 128 + rd * 16 + c15;
            const size_t idx = (size_t)(b * CH + c) * NTOK + q0 + q;
            out[idx] = x[idx] + O * invl;
        }
        __syncthreads();
    }
}

extern "C" void kernel_launch(void* const* d_in, const int* in_sizes, int n_in,
                              void* d_out, int out_size, void* d_ws, size_t ws_size,
                              hipStream_t stream) {
    const float* x  = (const float*)d_in[0];
    const float* Wq = (const float*)d_in[1];
    const float* bq = (const float*)d_in[2];
    const float* Wk = (const float*)d_in[3];
    const float* bk = (const float*)d_in[4];
    const float* Wv = (const float*)d_in[5];
    const float* bv = (const float*)d_in[6];
    float* out = (float*)d_out;

    unsigned short* Qh  = (unsigned short*)d_ws;                 // [B,N,32] bf16
    unsigned short* Kh  = Qh  + (size_t)BATCH * NTOK * DQK;      // [B,N,32] bf16
    unsigned short* Vh  = Kh  + (size_t)BATCH * NTOK * DQK;      // [B,C,N] bf16
    unsigned short* Wbf = Vh  + (size_t)BATCH * CH * NTOK;       // [320,256] bf16
    unsigned int*   Mk  = (unsigned int*)(Wbf + 320 * 256);      // [B] max||k||^2

    wconv<<<dim3(80), dim3(256), 0, stream>>>(Wq, Wk, Wv, Wbf, Mk);
    qkv_proj<<<dim3(1024), dim3(256), 0, stream>>>(x, bq, bk, bv, Wbf,
                                                   Qh, Kh, Vh, Mk);
    attn<<<dim3(256), dim3(512), 0, stream>>>(x, Qh, Kh, Vh, Mk, out);
}